// Round 14
// baseline (131.766 us; speedup 1.0000x reference)
//
#include <hip/hip_runtime.h>
#include <hip/hip_bf16.h>

#define N_NODES 1536
#define NF 64
#define NOUT 64
#define FIN 65
#define TI 6

typedef __bf16 bf16x8 __attribute__((ext_vector_type(8)));
typedef float f32x4 __attribute__((ext_vector_type(4)));

// One block: TI=6 i-rows x 128 j-cols. Swapped-operand MFMA
//   D[o][j] = sum_k W[o][k] * |feat[j][k]-feat[i][k]|
// THE experiment: 16 waves/CU (4 blocks/CU via launch_bounds(256,4),
// grid 3072 = exactly 3 rounds) vs R9's 12 waves/CU at identical round
// structure — isolates per-CU outstanding-store capacity (Little's law:
// per-CU write BW = in-flight bytes / completion latency; each wave caps
// at ~8-16 outstanding stores, so more waves = more in-flight).
// VGPR diet to fit the 128-reg cap: feat fragments pre-rounded to bf16
// (diff of two bf16 is exact in f32 -> absmax unchanged, verified R13).
// All global reads hoisted to kernel start (adj+feat slabs in LDS); loop
// body is DS ops + stores only. Epilogue transposes each wave's 32j x 64o
// tile through wave-private XOR-swizzled LDS so global stores are 1 KB
// lane-contiguous full lines. LDS: 32 + 1.5 + 3 = 36.5 KB (x4 = 146/CU).
__global__ __launch_bounds__(256, 4)
void edge_gcn_mfma(const float* __restrict__ feat,
                   const float* __restrict__ adj,
                   const float* __restrict__ W,
                   const float* __restrict__ b,
                   float* __restrict__ out)
{
    const int tid  = threadIdx.x;
    const int lane = tid & 63;
    const int wv   = tid >> 6;          // wave 0..3
    const int l15  = lane & 15;
    const int lg   = lane >> 4;         // 0..3

    const int i0 = blockIdx.y * TI;
    const int j0 = blockIdx.x * 128;
    const int jw = j0 + wv * 32;        // this wave's 32 j's

    __shared__ float lds[8192];         // 4 waves x 8 KB transpose buffers
    __shared__ float fslab[TI * NF];    // 6 x 64 feat i-slab (1.5 KB)
    __shared__ float aslab[TI * 128];   // 6 x 128 adj tile (3 KB)
    float* const lbase = lds + wv * 2048;

    // ---- cooperative feat i-slab load: 6 rows x 64 f32 = 96 f32x4 ----
    if (tid < 96) {
        const int row = tid >> 4;            // 0..5
        const int col = (tid & 15) * 4;      // 0..60
        *reinterpret_cast<f32x4*>(&fslab[row * NF + col]) =
            *reinterpret_cast<const f32x4*>(
                &feat[(size_t)(i0 + row) * NF + col]);
    }
    // ---- cooperative adj tile load: 6 rows x 128 f32 = 192 f32x4 ----
    if (tid < 192) {
        const int row = tid >> 5;            // 0..5
        const int col = (tid & 31) * 4;      // 0..124
        *reinterpret_cast<f32x4*>(&aslab[row * 128 + col]) =
            *reinterpret_cast<const f32x4*>(
                &adj[(size_t)(i0 + row) * N_NODES + j0 + col]);
    }

    // ---- A fragments (W): once per block ----
    bf16x8 afrag[2][4];                 // [kk][mo]
#pragma unroll
    for (int kk = 0; kk < 2; ++kk) {
#pragma unroll
        for (int mo = 0; mo < 4; ++mo) {
            const float* wp = W + (mo * 16 + l15) * FIN + kk * 32 + lg * 8;
#pragma unroll
            for (int e = 0; e < 8; ++e) afrag[kk][mo][e] = (__bf16)wp[e];
        }
    }

    // ---- feat[j] fragments, pre-rounded bf16 (8 VGPRs) ----
    bf16x8 fjrb[2][2];                  // [n][kk]
#pragma unroll
    for (int n = 0; n < 2; ++n) {
        const float* fjrow = feat + (jw + n * 16 + l15) * NF;
#pragma unroll
        for (int kk = 0; kk < 2; ++kk)
#pragma unroll
            for (int e = 0; e < 8; ++e)
                fjrb[n][kk][e] = (__bf16)fjrow[kk * 32 + lg * 8 + e];
    }

    // ---- epilogue-B constants: o = l15*4 + r ----
    float wlB[4], bvB[4];
#pragma unroll
    for (int r = 0; r < 4; ++r) {
        wlB[r] = W[(l15 * 4 + r) * FIN + NF];
        bvB[r] = b[l15 * 4 + r];
    }

    __syncthreads();                    // slabs ready; only barrier

    // ---- i loop (rolled; body has NO global loads) ----
#pragma unroll 1
    for (int ii = 0; ii < TI; ++ii) {
        const int i = i0 + ii;

        bf16x8 fib[2];                  // fi from LDS, pre-rounded bf16
#pragma unroll
        for (int kk = 0; kk < 2; ++kk) {
            const float* fp = &fslab[ii * NF + kk * 32 + lg * 8];
#pragma unroll
            for (int e = 0; e < 8; ++e) fib[kk][e] = (__bf16)fp[e];
        }

        f32x4 acc[4][2];                // [mo][n]
#pragma unroll
        for (int mo = 0; mo < 4; ++mo)
#pragma unroll
            for (int n = 0; n < 2; ++n)
                acc[mo][n] = (f32x4){0.f, 0.f, 0.f, 0.f};

#pragma unroll
        for (int n = 0; n < 2; ++n) {
#pragma unroll
            for (int kk = 0; kk < 2; ++kk) {
                bf16x8 bfrag;
#pragma unroll
                for (int e = 0; e < 8; ++e)
                    bfrag[e] = (__bf16)fabsf((float)fjrb[n][kk][e] -
                                             (float)fib[kk][e]);
#pragma unroll
                for (int mo = 0; mo < 4; ++mo)
                    acc[mo][n] = __builtin_amdgcn_mfma_f32_16x16x32_bf16(
                        afrag[kk][mo], bfrag, acc[mo][n], 0, 0, 0);
            }
        }

        // ---- epilogue A: raw acc -> transposed LDS tile ----
        // tile T[j(32)][o(64)], float off = j*64 + (o ^ ((j&7)<<2))
#pragma unroll
        for (int n = 0; n < 2; ++n) {
            const int jrow = n * 16 + l15;
#pragma unroll
            for (int mo = 0; mo < 4; ++mo) {
                const int swz = (mo * 16 + lg * 4) ^ ((l15 & 7) << 2);
                *reinterpret_cast<f32x4*>(lbase + jrow * 64 + swz) = acc[mo][n];
            }
        }

        // ---- epilogue B: finalize (+adj*W64 +bias) + 1 KB stores ----
#pragma unroll
        for (int t = 0; t < 8; ++t) {
            const int jr = t * 4 + lg;
            const int oo = l15 * 4;
            f32x4 v = *reinterpret_cast<const f32x4*>(
                lbase + jr * 64 + (oo ^ ((jr & 7) << 2)));
            const float av = aslab[ii * 128 + wv * 32 + jr];
#pragma unroll
            for (int r = 0; r < 4; ++r)
                v[r] = v[r] + av * wlB[r] + bvB[r];
            float* op = out + ((size_t)i * N_NODES + jw + jr) * NOUT + oo;
            *reinterpret_cast<f32x4*>(op) = v;
        }
    }
}

extern "C" void kernel_launch(void* const* d_in, const int* in_sizes, int n_in,
                              void* d_out, int out_size, void* d_ws, size_t ws_size,
                              hipStream_t stream) {
    const float* feat = (const float*)d_in[0];   // [1536][64]
    const float* adj  = (const float*)d_in[1];   // [1536][1536]
    const float* W    = (const float*)d_in[2];   // [64][65]
    const float* b    = (const float*)d_in[3];   // [64]
    float* out = (float*)d_out;                  // [1536*1536][64]

    dim3 grid(N_NODES / 128, N_NODES / TI);
    dim3 block(256);
    edge_gcn_mfma<<<grid, block, 0, stream>>>(feat, adj, W, b, out);
}

// Round 15
// 128.326 us; speedup vs baseline: 1.0268x; 1.0268x over previous
//
#include <hip/hip_runtime.h>
#include <hip/hip_bf16.h>

#define N_NODES 1536
#define NF 64
#define NOUT 64
#define FIN 65
#define TI 12

typedef __bf16 bf16x8 __attribute__((ext_vector_type(8)));
typedef float f32x4 __attribute__((ext_vector_type(4)));

// Producer-consumer wave specialization. One block: TI=12 i-rows x 128 j.
//   D[o][j] = sum_k W[o][k] * |feat[j][k]-feat[i][k]|
// Waves 0-1 (producers): MFMA-compute 64 j's each into a double-buffered
// 2 x 32 KB LDS tile (XOR-swizzled, row&7). Waves 2-3 (consumers): PURE
// store loops -- ds_read + finalize(+adj*W64+bias) + 1 KB contiguous
// stores, 16 KB/iter each, mimicking the memset control's ~100% store
// duty cycle (every prior variant gave each wave a compute phase during
// which the CU's write queue drained empty -> 4.95 vs 6.8 TB/s).
// Sync: raw s_barrier + explicit lgkmcnt(0) + sched_barrier(0) -- NOT
// __syncthreads, whose implicit vmcnt(0) would force consumers to fully
// drain their stores every iteration. Double buffer makes iter ii's fill
// concurrent with iter ii-1's drain. All global reads hoisted to setup.
// LDS: 64 (2 tile bufs) + 3 (fslab) + 6 (aslab) = 73 KB; x2 blocks = 146/CU.
// Grid 12 x 128 = 1536 blocks = exactly 3 rounds at 2 blocks/CU.
__global__ __launch_bounds__(256, 2)
void edge_gcn_mfma(const float* __restrict__ feat,
                   const float* __restrict__ adj,
                   const float* __restrict__ W,
                   const float* __restrict__ b,
                   float* __restrict__ out)
{
    const int tid  = threadIdx.x;
    const int lane = tid & 63;
    const int wv   = tid >> 6;          // wave 0..3
    const int l15  = lane & 15;
    const int lg   = lane >> 4;         // 0..3

    const int i0 = blockIdx.y * TI;
    const int j0 = blockIdx.x * 128;

    __shared__ float buf[2][128 * 64];  // double-buffered 128j x 64o tiles
    __shared__ float fslab[TI * NF];    // 12 x 64 feat i-slab (3 KB)
    __shared__ float aslab[TI * 128];   // 12 x 128 adj tile (6 KB)

    // ---- cooperative setup loads (all waves) ----
    if (tid < 192) {                    // fslab: 192 f32x4
        const int row = tid >> 4;
        const int col = (tid & 15) * 4;
        *reinterpret_cast<f32x4*>(&fslab[row * NF + col]) =
            *reinterpret_cast<const f32x4*>(
                &feat[(size_t)(i0 + row) * NF + col]);
    }
#pragma unroll
    for (int h = 0; h < 2; ++h) {       // aslab: 384 f32x4
        const int idx = h * 256 + tid;
        if (idx < 384) {
            const int row = idx >> 5;
            const int col = (idx & 31) * 4;
            *reinterpret_cast<f32x4*>(&aslab[row * 128 + col]) =
                *reinterpret_cast<const f32x4*>(
                    &adj[(size_t)(i0 + row) * N_NODES + j0 + col]);
        }
    }

    // ---- role-specific setup ----
    bf16x8 afrag[2][4];                 // producers: W fragments [kk][mo]
    bf16x8 fjrb[4][2];                  // producers: feat[j] bf16 [n][kk]
    float wlB[4], bvB[4];               // consumers: adj-col W + bias

    if (wv < 2) {
        const int cw = wv;              // producer index: j-half cw*64
#pragma unroll
        for (int kk = 0; kk < 2; ++kk)
#pragma unroll
            for (int mo = 0; mo < 4; ++mo) {
                const float* wp = W + (mo * 16 + l15) * FIN + kk * 32 + lg * 8;
#pragma unroll
                for (int e = 0; e < 8; ++e) afrag[kk][mo][e] = (__bf16)wp[e];
            }
#pragma unroll
        for (int n = 0; n < 4; ++n) {
            const float* fjrow =
                feat + (size_t)(j0 + cw * 64 + n * 16 + l15) * NF;
#pragma unroll
            for (int kk = 0; kk < 2; ++kk)
#pragma unroll
                for (int e = 0; e < 8; ++e)
                    fjrb[n][kk][e] = (__bf16)fjrow[kk * 32 + lg * 8 + e];
        }
    } else {
#pragma unroll
        for (int r = 0; r < 4; ++r) {
            wlB[r] = W[(l15 * 4 + r) * FIN + NF];
            bvB[r] = b[l15 * 4 + r];
        }
    }

    __syncthreads();                    // slabs ready (one full-drain is ok)

    // ---- consumer drain helper: 64 rows x 64o = 16 KB per wave ----
    auto drain = [&](int jj) {
        const int sw = wv - 2;          // consumer index: j-half sw*64
        const float* lb = &buf[jj & 1][0];
        float* const orow =
            out + ((size_t)(i0 + jj) * N_NODES + j0 + sw * 64) * NOUT + l15 * 4;
#pragma unroll
        for (int t = 0; t < 16; ++t) {
            const int jr  = t * 4 + lg;          // row within this half
            const int row = sw * 64 + jr;        // row within buffer
            f32x4 v = *reinterpret_cast<const f32x4*>(
                lb + row * 64 + ((l15 * 4) ^ ((row & 7) << 2)));
            const float av = aslab[jj * 128 + row];
#pragma unroll
            for (int r = 0; r < 4; ++r)
                v[r] = v[r] + av * wlB[r] + bvB[r];
            *reinterpret_cast<f32x4*>(orow + jr * NOUT) = v;
        }
    };

    // ---- main loop: fill buf[ii&1] while draining buf[(ii-1)&1] ----
#pragma unroll 1
    for (int ii = 0; ii < TI; ++ii) {
        if (wv < 2) {
            const int cw = wv;
            bf16x8 fib[2];              // feat[i] from LDS, bf16
#pragma unroll
            for (int kk = 0; kk < 2; ++kk) {
                const float* fp = &fslab[ii * NF + kk * 32 + lg * 8];
#pragma unroll
                for (int e = 0; e < 8; ++e) fib[kk][e] = (__bf16)fp[e];
            }

            f32x4 acc[4][4];            // [mo][n]
#pragma unroll
            for (int mo = 0; mo < 4; ++mo)
#pragma unroll
                for (int n = 0; n < 4; ++n)
                    acc[mo][n] = (f32x4){0.f, 0.f, 0.f, 0.f};

#pragma unroll
            for (int n = 0; n < 4; ++n) {
#pragma unroll
                for (int kk = 0; kk < 2; ++kk) {
                    bf16x8 bfrag;
#pragma unroll
                    for (int e = 0; e < 8; ++e)
                        bfrag[e] = (__bf16)fabsf((float)fjrb[n][kk][e] -
                                                 (float)fib[kk][e]);
#pragma unroll
                    for (int mo = 0; mo < 4; ++mo)
                        acc[mo][n] = __builtin_amdgcn_mfma_f32_16x16x32_bf16(
                            afrag[kk][mo], bfrag, acc[mo][n], 0, 0, 0);
                }
            }

            // transposed+swizzled tile write: rows cw*64 + n*16 + l15
            float* lb = &buf[ii & 1][0];
#pragma unroll
            for (int n = 0; n < 4; ++n) {
                const int row = cw * 64 + n * 16 + l15;
#pragma unroll
                for (int mo = 0; mo < 4; ++mo) {
                    const int swz = (mo * 16 + lg * 4) ^ ((row & 7) << 2);
                    *reinterpret_cast<f32x4*>(lb + row * 64 + swz) = acc[mo][n];
                }
            }
        } else if (ii > 0) {
            drain(ii - 1);
        }

        asm volatile("s_waitcnt lgkmcnt(0)" ::: "memory");
        __builtin_amdgcn_sched_barrier(0);
        __builtin_amdgcn_s_barrier();   // raw: no implicit vmcnt(0) drain
    }
    if (wv >= 2) drain(TI - 1);
}

extern "C" void kernel_launch(void* const* d_in, const int* in_sizes, int n_in,
                              void* d_out, int out_size, void* d_ws, size_t ws_size,
                              hipStream_t stream) {
    const float* feat = (const float*)d_in[0];   // [1536][64]
    const float* adj  = (const float*)d_in[1];   // [1536][1536]
    const float* W    = (const float*)d_in[2];   // [64][65]
    const float* b    = (const float*)d_in[3];   // [64]
    float* out = (float*)d_out;                  // [1536*1536][64]

    dim3 grid(N_NODES / 128, N_NODES / TI);
    dim3 block(256);
    edge_gcn_mfma<<<grid, block, 0, stream>>>(feat, adj, W, b, out);
}